// Round 10
// baseline (263.156 us; speedup 1.0000x reference)
//
#include <hip/hip_runtime.h>
#include <stdint.h>

#define K_DIM 4096
#define N_DIM 11008
#define NCOL  1376   // N/8

typedef __attribute__((ext_vector_type(4))) float  f32x4;
typedef __attribute__((ext_vector_type(8))) __bf16 bf16x8;

__device__ __forceinline__ void gload_lds16(const void* g, void* l) {
  __builtin_amdgcn_global_load_lds((const __attribute__((address_space(1))) void*)g,
                                   (__attribute__((address_space(3))) void*)l,
                                   16, 0, 0);
}

// ---------- prologue 1: x fp32 -> bf16 ----------
__global__ void __launch_bounds__(256) convert_x_kernel(const float* __restrict__ x,
                                                        __bf16* __restrict__ a) {
  size_t i = ((size_t)blockIdx.x * 256u + threadIdx.x) * 8u;
  f32x4 v0 = *(const f32x4*)(x + i);
  f32x4 v1 = *(const f32x4*)(x + i + 4);
  bf16x8 o;
  o[0] = (__bf16)v0[0]; o[1] = (__bf16)v0[1]; o[2] = (__bf16)v0[2]; o[3] = (__bf16)v0[3];
  o[4] = (__bf16)v1[0]; o[5] = (__bf16)v1[1]; o[6] = (__bf16)v1[2]; o[7] = (__bf16)v1[3];
  *(bf16x8*)(a + i) = o;
}

// ---------- prologue 2: AWQ dequant -> Wt bf16 [N][K] (transposed via LDS) ----------
__global__ void __launch_bounds__(256) dequant_kernel(const int* __restrict__ qw,
                                                      const int* __restrict__ qz,
                                                      const float* __restrict__ sc,
                                                      __bf16* __restrict__ wt) {
  constexpr int SH[8] = {0, 16, 4, 20, 8, 24, 12, 28};  // AWQ [0,4,1,5,2,6,3,7]*4
  __shared__ __bf16 tile[64][72];
  const int bid = blockIdx.x;
  const int tk = bid & 63;
  const int tn = bid >> 6;
  const int k0 = tk * 64;
  const int c0 = tn * 8;
  const int t = threadIdx.x;
#pragma unroll
  for (int r = 0; r < 2; ++r) {
    int idx = r * 256 + t;
    int kk = idx >> 3;
    int cc = idx & 7;
    int k = k0 + kk;
    int c = c0 + cc;
    uint32_t q  = (uint32_t)qw[(size_t)k * NCOL + c];
    int g = k >> 7;
    uint32_t zq = (uint32_t)qz[(size_t)g * NCOL + c];
    const float* s = sc + (size_t)g * N_DIM + (size_t)c * 8;
#pragma unroll
    for (int j = 0; j < 8; ++j) {
      int wv = (int)((q >> SH[j]) & 15u) - (int)((zq >> SH[j]) & 15u);
      tile[cc * 8 + j][kk] = (__bf16)((float)wv * s[j]);
    }
  }
  __syncthreads();
  const int n0 = tn * 64;
#pragma unroll
  for (int r = 0; r < 2; ++r) {
    int idx = r * 256 + t;
    int row = idx >> 3;
    int kc = idx & 7;
    bf16x8 v = *(const bf16x8*)&tile[row][kc * 8];
    *(bf16x8*)(wt + (size_t)(n0 + row) * K_DIM + k0 + kc * 8) = v;
  }
}

// ---------- main GEMM: 128x128 tile, BK=32, DOUBLE-BUFFERED single-barrier loop ----------
// 4 waves (2M x 2N), per-wave 64x64 = 4x4 frags of 16x16x32 bf16 MFMA (1 kk).
// Loop: { stage(t+1 -> buf^1); ds_read+MFMA(buf); __syncthreads(); flip }.
// The syncthreads' implicit vmcnt(0) now drains loads issued ~310 compute-cy
// earlier (vs 0 cy in the R1/R7 stage->drain->compute loop) -> L2 latency
// covered; ONE barrier per K-tile (R7 had two). Race-free by construction:
// barrier at end of t-1 completes all reads of buf^1 before t's DMA overwrite.
// LDS dbuf 2x16KB = 32KB; regs ~124 (64 AGPR acc) -> 4 blk/CU, 16 waves/CU.
// LDS layout (BK=32, 64B logical rows -> pair-merged 128B lines, R5-measured
// 0 conflicts): row r, granule g (16B, g=k/8) at line L=r>>1,
// slot S = (((r&1)<<2)|g) ^ (L&7). Linear DMA dest + inverse-permuted global
// source (rule #21).
__global__ void __launch_bounds__(256, 4) wq_gemm_kernel(
    const __bf16* __restrict__ A,    // [M][K] bf16
    const __bf16* __restrict__ Wt,   // [N][K] bf16
    const float* __restrict__ bias,
    float* __restrict__ out,
    const int Mblk)
{
  __shared__ char lds[32768];   // 2 bufs x (A 8KB + B 8KB)

  const int nwg = gridDim.x;
  int bid = blockIdx.x;
  if ((nwg & 7) == 0) {                 // XCD-aware swizzle (1376 % 8 == 0, bijective)
    const int cpx = nwg >> 3;
    bid = (bid & 7) * cpx + (bid >> 3);
  }
  const int bm = bid % Mblk;            // m-fastest: XCD chunk reuses B panels in L2
  const int bn = bid / Mblk;
  const int m0 = bm * 128;
  const int n0 = bn * 128;

  const int t = threadIdx.x;
  const int lane = t & 63;
  const int w = t >> 6;      // 0..3
  const int wr = w >> 1;     // 0..1  (M half)
  const int wc = w & 1;      // 0..1  (N half)
  const int lrow = lane & 15;
  const int lk = lane >> 4;

  // staging decode (dest byte = cid*16, cid = i*256+t, i = 0,1):
  // L = cid>>3, S = cid&7; inv = S^(L&7); r = 2*(cid>>3)+(inv>>2); g = inv&3.
  // i-part: cid>>3 = i*32+(t>>3) -> (L&7) i-independent; r = i*64 + rbase.
  const int inv = (t & 7) ^ ((t >> 3) & 7);
  const int rbase = 2 * (t >> 3) + (inv >> 2);
  const uint32_t off0 = (uint32_t)rbase * K_DIM + (uint32_t)(inv & 3) * 8;
  const __bf16* pA = A  + (size_t)m0 * K_DIM + off0;
  const __bf16* pB = Wt + (size_t)n0 * K_DIM + off0;
  const int dst = t * 16;

  f32x4 acc[4][4];
#pragma unroll
  for (int i = 0; i < 4; ++i)
#pragma unroll
    for (int j = 0; j < 4; ++j) acc[i][j] = (f32x4){0.f, 0.f, 0.f, 0.f};

  // compute-side lane offset: row r = frag_base + lrow (frag_base % 16 == 0 ->
  // line&7 = (lrow>>1)&7, r&1 = lrow&1); byte = frag_base*64 + lane_off.
  const int lane_off = (lrow >> 1) * 128 +
                       ((((((lrow & 1) << 2) | lk)) ^ ((lrow >> 1) & 7)) << 4);
  const int aoff = wr * 4096 + lane_off;          // within A region
  const int boff = 8192 + wc * 4096 + lane_off;   // within B region

#define STAGE_TILE(BUF, KOFF) do { \
    char* _a = (BUF); \
    gload_lds16(pA + (KOFF),                       _a + dst); \
    gload_lds16(pA + (KOFF) + (size_t)(64 * K_DIM), _a + 4096 + dst); \
    gload_lds16(pB + (KOFF),                       _a + 8192 + dst); \
    gload_lds16(pB + (KOFF) + (size_t)(64 * K_DIM), _a + 12288 + dst); \
  } while (0)

  // prologue: stage tile 0 into buf 0
  STAGE_TILE(lds, 0u);
  __syncthreads();

  for (int kt = 0; kt < 128; ++kt) {
    char* curb = lds + (kt & 1) * 16384;
    char* nxtb = lds + ((kt + 1) & 1) * 16384;
    if (kt < 127) STAGE_TILE(nxtb, (uint32_t)(kt + 1) * 32);
    __builtin_amdgcn_sched_barrier(0);   // keep stage issue ahead of compute

    bf16x8 av[4], bv[4];
#pragma unroll
    for (int m = 0; m < 4; ++m) av[m] = *(const bf16x8*)(curb + aoff + m * 1024);
#pragma unroll
    for (int n = 0; n < 4; ++n) bv[n] = *(const bf16x8*)(curb + boff + n * 1024);
#pragma unroll
    for (int m = 0; m < 4; ++m)
#pragma unroll
      for (int n = 0; n < 4; ++n)
        acc[m][n] = __builtin_amdgcn_mfma_f32_16x16x32_bf16(av[m], bv[n], acc[m][n], 0, 0, 0);

    __syncthreads();   // drains vmcnt(0): next tile's DMA (issued ~310cy ago) lands
  }
#undef STAGE_TILE

  // epilogue: C/D layout col=lane&15, row=(lane>>4)*4+reg (m89-verified, R1-R9-passed)
  const int orow0 = m0 + wr * 64 + lk * 4;
  const int ocol0 = n0 + wc * 64 + lrow;
#pragma unroll
  for (int n = 0; n < 4; ++n) {
    const int col = ocol0 + n * 16;
    const float bv = bias[col];
#pragma unroll
    for (int m = 0; m < 4; ++m) {
      float* po = out + (size_t)(orow0 + m * 16) * N_DIM + col;
      po[0]                 = acc[m][n][0] + bv;
      po[(size_t)N_DIM]     = acc[m][n][1] + bv;
      po[2 * (size_t)N_DIM] = acc[m][n][2] + bv;
      po[3 * (size_t)N_DIM] = acc[m][n][3] + bv;
    }
  }
}

extern "C" void kernel_launch(void* const* d_in, const int* in_sizes, int n_in,
                              void* d_out, int out_size, void* d_ws, size_t ws_size,
                              hipStream_t stream) {
  const float* x    = (const float*)d_in[0];
  const int* qw     = (const int*)d_in[1];
  const int* qz     = (const int*)d_in[2];
  const float* sc   = (const float*)d_in[3];
  const float* bias = (const float*)d_in[4];
  float* out = (float*)d_out;

  const int M = in_sizes[0] / K_DIM;        // 2048
  const int Mblk = M / 128;                 // 16
  const int grid = Mblk * (N_DIM / 128);    // 1376 (divisible by 8)

  const size_t abytes = (size_t)M * K_DIM * 2;
  __bf16* Aw = (__bf16*)d_ws;
  __bf16* Wt = (__bf16*)((char*)d_ws + abytes);

  convert_x_kernel<<<(M * K_DIM) / 2048, 256, 0, stream>>>(x, Aw);
  dequant_kernel<<<(K_DIM / 64) * (N_DIM / 64), 256, 0, stream>>>(qw, qz, sc, Wt);

  wq_gemm_kernel<<<grid, 256, 0, stream>>>(Aw, Wt, bias, out, Mblk);
}

// Round 11
// 241.859 us; speedup vs baseline: 1.0881x; 1.0881x over previous
//
#include <hip/hip_runtime.h>
#include <stdint.h>

#define K_DIM 4096
#define N_DIM 11008
#define NCOL  1376   // N/8

typedef __attribute__((ext_vector_type(4))) float  f32x4;
typedef __attribute__((ext_vector_type(8))) __bf16 bf16x8;

__device__ __forceinline__ void gload_lds16(const void* g, void* l) {
  __builtin_amdgcn_global_load_lds((const __attribute__((address_space(1))) void*)g,
                                   (__attribute__((address_space(3))) void*)l,
                                   16, 0, 0);
}

// ---------- prologue 1: x fp32 -> bf16 ----------
__global__ void __launch_bounds__(256) convert_x_kernel(const float* __restrict__ x,
                                                        __bf16* __restrict__ a) {
  size_t i = ((size_t)blockIdx.x * 256u + threadIdx.x) * 8u;
  f32x4 v0 = *(const f32x4*)(x + i);
  f32x4 v1 = *(const f32x4*)(x + i + 4);
  bf16x8 o;
  o[0] = (__bf16)v0[0]; o[1] = (__bf16)v0[1]; o[2] = (__bf16)v0[2]; o[3] = (__bf16)v0[3];
  o[4] = (__bf16)v1[0]; o[5] = (__bf16)v1[1]; o[6] = (__bf16)v1[2]; o[7] = (__bf16)v1[3];
  *(bf16x8*)(a + i) = o;
}

// ---------- prologue 2: AWQ dequant -> Wt bf16 [N][K] (transposed via LDS) ----------
__global__ void __launch_bounds__(256) dequant_kernel(const int* __restrict__ qw,
                                                      const int* __restrict__ qz,
                                                      const float* __restrict__ sc,
                                                      __bf16* __restrict__ wt) {
  constexpr int SH[8] = {0, 16, 4, 20, 8, 24, 12, 28};  // AWQ [0,4,1,5,2,6,3,7]*4
  __shared__ __bf16 tile[64][72];
  const int bid = blockIdx.x;
  const int tk = bid & 63;
  const int tn = bid >> 6;
  const int k0 = tk * 64;
  const int c0 = tn * 8;
  const int t = threadIdx.x;
#pragma unroll
  for (int r = 0; r < 2; ++r) {
    int idx = r * 256 + t;
    int kk = idx >> 3;
    int cc = idx & 7;
    int k = k0 + kk;
    int c = c0 + cc;
    uint32_t q  = (uint32_t)qw[(size_t)k * NCOL + c];
    int g = k >> 7;
    uint32_t zq = (uint32_t)qz[(size_t)g * NCOL + c];
    const float* s = sc + (size_t)g * N_DIM + (size_t)c * 8;
#pragma unroll
    for (int j = 0; j < 8; ++j) {
      int wv = (int)((q >> SH[j]) & 15u) - (int)((zq >> SH[j]) & 15u);
      tile[cc * 8 + j][kk] = (__bf16)((float)wv * s[j]);
    }
  }
  __syncthreads();
  const int n0 = tn * 64;
#pragma unroll
  for (int r = 0; r < 2; ++r) {
    int idx = r * 256 + t;
    int row = idx >> 3;
    int kc = idx & 7;
    bf16x8 v = *(const bf16x8*)&tile[row][kc * 8];
    *(bf16x8*)(wt + (size_t)(n0 + row) * K_DIM + k0 + kc * 8) = v;
  }
}

// ---------- main GEMM: 128(M) x 256(N), BK=64, 4-phase counted-vmcnt, 3-buf ----------
// 8 waves (512 thr) as 2M x 4N, per-wave 64x64 = 4x4 frags of 16x16x32 bf16.
// T3+T4 schedule (the only measured escape from the m97 ~43% basin), with the
// capacity/eff lesson from R2-R10 applied: grid 16x43=688 @ 1 blk/CU -> eff
// 0.896 (R2's 256sq gave 344 @ 0.672 -- the entire loss).
// LDS = 3 K-tile buffers x 48KB = 144KB (A 16KB + B 32KB each): while tile t
// (buf t%3) computes, tile t+1 sits landed in buf (t+1)%3 and tile t+2 streams
// into buf (t+2)%3. ONE s_waitcnt vmcnt(6) per K-tile (never 0 in steady
// state); issue-to-wait distance 4-8 phases (~1200-2500 cy) covers HBM.
// Per K-tile: 4 phases, each {ds_read subtile || 1-2 stage issues; barrier;
// lgkmcnt(0); setprio(1); 8 MFMA; setprio(0); barrier}.
// Granule-XOR swizzle (0 conflicts R1-R10): row r, granule g stored at
// physical g^(r&7); linear DMA dest + inverse-swizzled source (rule #21).
__global__ void __launch_bounds__(512, 2) wq_gemm_kernel(
    const __bf16* __restrict__ A,    // [M][K] bf16
    const __bf16* __restrict__ Wt,   // [N][K] bf16
    const float* __restrict__ bias,
    float* __restrict__ out,
    const int Mblk)
{
  extern __shared__ char lds[];   // 3 x 49152

  const int nwg = gridDim.x;
  int bid = blockIdx.x;
  if ((nwg & 7) == 0) {                 // XCD-aware swizzle (688 % 8 == 0, bijective)
    const int cpx = nwg >> 3;
    bid = (bid & 7) * cpx + (bid >> 3);
  }
  const int bm = bid % Mblk;            // m-fastest: XCD chunk reuses B panels in L2
  const int bn = bid / Mblk;
  const int m0 = bm * 128;
  const int n0 = bn * 256;

  const int t = threadIdx.x;   // 0..511
  const int lane = t & 63;
  const int w = t >> 6;        // 0..7
  const int wm = w >> 2;       // 0..1  (M half)
  const int wn = w & 3;        // 0..3  (N quarter)
  const int lrow = lane & 15;
  const int lk = lane >> 4;

  // staging decode (R9-verified): round covers 64 rows; dest byte = cid*16;
  // source granule gl = (t&7)^((t>>3)&7), row offset (t>>3) within round.
  const int gl = (t & 7) ^ ((t >> 3) & 7);
  const uint32_t off0 = (uint32_t)(t >> 3) * K_DIM + (uint32_t)gl * 8;
  const __bf16* pA = A  + (size_t)m0 * K_DIM + off0;
  const __bf16* pB = Wt + (size_t)n0 * K_DIM + off0;
  const int dst = t * 16;

#define STG_A(NB, KO, I) gload_lds16(pA + (KO) + (size_t)(I) * (64 * K_DIM), (NB) + (I) * 8192 + dst)
#define STG_B(NB, KO, J) gload_lds16(pB + (KO) + (size_t)(J) * (64 * K_DIM), (NB) + 16384 + (J) * 8192 + dst)

  f32x4 acc[4][4];
#pragma unroll
  for (int i = 0; i < 4; ++i)
#pragma unroll
    for (int j = 0; j < 4; ++j) acc[i][j] = (f32x4){0.f, 0.f, 0.f, 0.f};

  // prologue: T0 -> buf0 (6 loads), T1 -> buf1 (6 loads); wait T0, keep T1 in flight
  {
    char* b0 = lds;
    char* b1 = lds + 49152;
    STG_A(b0, 0u, 0); STG_A(b0, 0u, 1);
    STG_B(b0, 0u, 0); STG_B(b0, 0u, 1); STG_B(b0, 0u, 2); STG_B(b0, 0u, 3);
    STG_A(b1, 64u, 0); STG_A(b1, 64u, 1);
    STG_B(b1, 64u, 0); STG_B(b1, 64u, 1); STG_B(b1, 64u, 2); STG_B(b1, 64u, 3);
    asm volatile("s_waitcnt vmcnt(6)" ::: "memory");
    __builtin_amdgcn_s_barrier();
  }

  // compute-side constants (row&7 == lrow&7: all frag row bases are multiples of 16)
  const int gk0 = (lk ^ (lrow & 7)) << 4;        // kk=0 granule byte offset
  const int gk1 = ((4 + lk) ^ (lrow & 7)) << 4;  // kk=1
  const int arow = (wm * 64 + lrow) * 128;
  const int brow = 16384 + (wn * 64 + lrow) * 128;

#define MFMA2(MARR, B0, B1, N0) do { \
    _Pragma("unroll") \
    for (int _m = 0; _m < 4; ++_m) { \
      acc[_m][(N0)]     = __builtin_amdgcn_mfma_f32_16x16x32_bf16(MARR[_m], (B0), acc[_m][(N0)], 0, 0, 0); \
      acc[_m][(N0) + 1] = __builtin_amdgcn_mfma_f32_16x16x32_bf16(MARR[_m], (B1), acc[_m][(N0) + 1], 0, 0, 0); \
    } } while (0)

  int cur = 0;
  for (int kt = 0; kt < 64; ++kt) {
    char* cb = lds + cur * 49152;
    int nst = cur + 2; if (nst >= 3) nst -= 3;   // (kt+2) % 3
    char* nb = lds + nst * 49152;
    const uint32_t ko = (uint32_t)(kt + 2) * 64;
    const char* ab = cb + arow;
    const char* bb = cb + brow;
    const bool stg = (kt < 62);

    bf16x8 a0[4], q0, q1;
    // ---- P1: kk0, n0-1 ----
#pragma unroll
    for (int m = 0; m < 4; ++m) a0[m] = *(const bf16x8*)(ab + m * 2048 + gk0);
    q0 = *(const bf16x8*)(bb + gk0);
    q1 = *(const bf16x8*)(bb + 2048 + gk0);
    if (stg) { STG_A(nb, ko, 0); STG_A(nb, ko, 1); }
    __builtin_amdgcn_s_barrier();
    asm volatile("s_waitcnt lgkmcnt(0)");
    __builtin_amdgcn_s_setprio(1);
    MFMA2(a0, q0, q1, 0);
    __builtin_amdgcn_s_setprio(0);
    __builtin_amdgcn_s_barrier();

    // ---- P2: kk0, n2-3 (a0 reused from registers) ----
    q0 = *(const bf16x8*)(bb + 2 * 2048 + gk0);
    q1 = *(const bf16x8*)(bb + 3 * 2048 + gk0);
    if (stg) { STG_B(nb, ko, 0); }
    __builtin_amdgcn_s_barrier();
    asm volatile("s_waitcnt lgkmcnt(0)");
    __builtin_amdgcn_s_setprio(1);
    MFMA2(a0, q0, q1, 2);
    __builtin_amdgcn_s_setprio(0);
    __builtin_amdgcn_s_barrier();

    // ---- P3: kk1, n0-1 ----
#pragma unroll
    for (int m = 0; m < 4; ++m) a0[m] = *(const bf16x8*)(ab + m * 2048 + gk1);
    q0 = *(const bf16x8*)(bb + gk1);
    q1 = *(const bf16x8*)(bb + 2048 + gk1);
    if (stg) { STG_B(nb, ko, 1); STG_B(nb, ko, 2); }
    __builtin_amdgcn_s_barrier();
    asm volatile("s_waitcnt lgkmcnt(0)");
    __builtin_amdgcn_s_setprio(1);
    MFMA2(a0, q0, q1, 0);
    __builtin_amdgcn_s_setprio(0);
    __builtin_amdgcn_s_barrier();

    // ---- P4: kk1, n2-3 ----
    q0 = *(const bf16x8*)(bb + 2 * 2048 + gk1);
    q1 = *(const bf16x8*)(bb + 3 * 2048 + gk1);
    if (stg) { STG_B(nb, ko, 3); }
    __builtin_amdgcn_s_barrier();
    asm volatile("s_waitcnt lgkmcnt(0)");
    __builtin_amdgcn_s_setprio(1);
    MFMA2(a0, q0, q1, 2);
    __builtin_amdgcn_s_setprio(0);
    // counted drain: T(kt+1) landed, T(kt+2)'s 6 loads stay in flight
    if (kt < 62)       { asm volatile("s_waitcnt vmcnt(6)" ::: "memory"); }
    else if (kt == 62) { asm volatile("s_waitcnt vmcnt(0)" ::: "memory"); }
    __builtin_amdgcn_s_barrier();

    cur = (cur == 2) ? 0 : cur + 1;
  }
#undef MFMA2
#undef STG_A
#undef STG_B

  // epilogue: C/D layout col=lane&15, row=(lane>>4)*4+reg (m89-verified, R1-R10-passed)
  const int orow0 = m0 + wm * 64 + lk * 4;
  const int ocol0 = n0 + wn * 64 + lrow;
#pragma unroll
  for (int n = 0; n < 4; ++n) {
    const int col = ocol0 + n * 16;
    const float bv = bias[col];
#pragma unroll
    for (int m = 0; m < 4; ++m) {
      float* po = out + (size_t)(orow0 + m * 16) * N_DIM + col;
      po[0]                 = acc[m][n][0] + bv;
      po[(size_t)N_DIM]     = acc[m][n][1] + bv;
      po[2 * (size_t)N_DIM] = acc[m][n][2] + bv;
      po[3 * (size_t)N_DIM] = acc[m][n][3] + bv;
    }
  }
}

extern "C" void kernel_launch(void* const* d_in, const int* in_sizes, int n_in,
                              void* d_out, int out_size, void* d_ws, size_t ws_size,
                              hipStream_t stream) {
  const float* x    = (const float*)d_in[0];
  const int* qw     = (const int*)d_in[1];
  const int* qz     = (const int*)d_in[2];
  const float* sc   = (const float*)d_in[3];
  const float* bias = (const float*)d_in[4];
  float* out = (float*)d_out;

  const int M = in_sizes[0] / K_DIM;        // 2048
  const int Mblk = M / 128;                 // 16
  const int grid = Mblk * (N_DIM / 256);    // 16 * 43 = 688 (divisible by 8)

  const size_t abytes = (size_t)M * K_DIM * 2;
  __bf16* Aw = (__bf16*)d_ws;
  __bf16* Wt = (__bf16*)((char*)d_ws + abytes);

  convert_x_kernel<<<(M * K_DIM) / 2048, 256, 0, stream>>>(x, Aw);
  dequant_kernel<<<(K_DIM / 64) * (N_DIM / 64), 256, 0, stream>>>(qw, qz, sc, Wt);

  hipFuncSetAttribute((const void*)wq_gemm_kernel,
                      hipFuncAttributeMaxDynamicSharedMemorySize, 147456);
  wq_gemm_kernel<<<grid, 512, 147456, stream>>>(Aw, Wt, bias, out, Mblk);
}